// Round 3
// baseline (74.950 us; speedup 1.0000x reference)
//
#include <hip/hip_runtime.h>
#include <hip/hip_bf16.h>

#define HW 9216
#define CDIM 128
#define ROWS_W 64                  // rows per wave (4 m-fragments)
#define COLS_W 256                 // cols per wave-task
#define NGRP 16                    // 16-col groups per task
#define GRID_I (HW / (ROWS_W * 4)) // 36 (4 waves stacked per block)
#define GRID_J (HW / COLS_W)       // 36
#define NPART (GRID_I * GRID_J * 4)// 5184 per-wave partial pairs

using bf16 = __hip_bfloat16;
typedef __attribute__((ext_vector_type(4))) float f32x4;
typedef __attribute__((ext_vector_type(8))) short s16x8;

// exp(d/0.04) = exp2(d * log2(e)/0.04); scale folded into feat1 at prep time
#define EXP_SCALE 36.067376022224085f

// ---------------------------------------------------------------------------
// Kernel 1: x[b] [C][HW] f32 -> feat[b] [HW][C] bf16 (feat1 pre-scaled).
// ---------------------------------------------------------------------------
__global__ __launch_bounds__(256) void prep_kernel(const float* __restrict__ x,
                                                   bf16* __restrict__ feat) {
    __shared__ float tile[64][65];
    const float* xs = x + (size_t)blockIdx.z * CDIM * HW;
    bf16* fs = feat + (size_t)blockIdx.z * HW * CDIM;
    float scale = (blockIdx.z == 0) ? EXP_SCALE : 1.0f;

    int p0 = blockIdx.x * 64;
    int c0 = blockIdx.y * 64;
    int t  = threadIdx.x;

    int pc = t & 63;
    int cr = t >> 6;
#pragma unroll
    for (int i = 0; i < 16; ++i) {
        int cl = cr + i * 4;
        tile[cl][pc] = xs[(size_t)(c0 + cl) * HW + p0 + pc];
    }
    __syncthreads();

    int cc = t & 63;
    int pr = t >> 6;
#pragma unroll
    for (int i = 0; i < 16; ++i) {
        int pl = pr + i * 4;
        fs[(size_t)(p0 + pl) * CDIM + c0 + cc] = __float2bfloat16(tile[cc][pl] * scale);
    }
}

// ---------------------------------------------------------------------------
// Kernel 2: barrier-free, LDS-free. Wave = 64 rows x 256 cols.
// A frags + row labels register-resident; B frags streamed from L2 in
// 16-col groups with 2-deep double buffer; immediate exp/mask epilogue.
// grid = (36, 36), block = 256 (4 independent waves). Per-wave partials.
// ---------------------------------------------------------------------------
__global__ __launch_bounds__(256) void simsum_kernel(const bf16* __restrict__ feat1,
                                                     const bf16* __restrict__ feat2,
                                                     const int* __restrict__ label,
                                                     float* __restrict__ partials) {
    int t    = threadIdx.x;
    int w    = t >> 6;
    int lane = t & 63;
    int lr   = lane & 15;        // fragment row/col lane index
    int kg   = lane >> 4;        // 0..3 k-subgroup

    int r0 = (blockIdx.x * 4 + w) * ROWS_W;
    int c0 = blockIdx.y * COLS_W;

    // A fragments (pre-scaled feat1), persistent: af[m][ks]
    s16x8 af[4][4];
#pragma unroll
    for (int m = 0; m < 4; ++m) {
        const bf16* arow = &feat1[(size_t)(r0 + m * 16 + lr) * CDIM + kg * 8];
#pragma unroll
        for (int ks = 0; ks < 4; ++ks)
            af[m][ks] = *(const s16x8*)(arow + ks * 32);
    }

    // row labels for accumulator rows: row = r0 + m*16 + kg*4 + r2
    int g1v[4][4];
#pragma unroll
    for (int m = 0; m < 4; ++m)
#pragma unroll
        for (int r2 = 0; r2 < 4; ++r2)
            g1v[m][r2] = label[r0 + m * 16 + kg * 4 + r2];

    const int* lab2 = label + HW;
    float tot = 0.f, pos = 0.f;

    s16x8 bA[4], bB[4];
    int gA, gB;

    // B-group loader: 16 cols (rows of feat2) x K=128, + column label
    auto loadB = [&](s16x8 (&buf)[4], int& g2, int grp) {
        int j = c0 + grp * 16 + lr;
        const bf16* brow = &feat2[(size_t)j * CDIM + kg * 8];
#pragma unroll
        for (int ks = 0; ks < 4; ++ks)
            buf[ks] = *(const s16x8*)(brow + ks * 32);
        g2 = lab2[j];
    };

    // process one 16-col group: 16 MFMAs (4 indep chains) + epilogue
    auto process = [&](const s16x8 (&buf)[4], int g2) {
#pragma unroll
        for (int m = 0; m < 4; ++m) {
            f32x4 a = {0.f, 0.f, 0.f, 0.f};
#pragma unroll
            for (int ks = 0; ks < 4; ++ks)
                a = __builtin_amdgcn_mfma_f32_16x16x32_bf16(af[m][ks], buf[ks], a, 0, 0, 0);
#pragma unroll
            for (int r2 = 0; r2 < 4; ++r2) {
                float e = exp2f(a[r2]);
                tot += e;
                pos += (g1v[m][r2] == g2) ? e : 0.f;
            }
        }
    };

    loadB(bA, gA, 0);
#pragma unroll
    for (int ii = 0; ii < NGRP; ii += 2) {
        loadB(bB, gB, ii + 1);
        process(bA, gA);
        loadB(bA, gA, (ii + 2 < NGRP) ? ii + 2 : 0);  // wrap-prefetch: harmless
        process(bB, gB);
    }

    // wave reduce -> per-wave partial
#pragma unroll
    for (int off = 32; off; off >>= 1) {
        tot += __shfl_down(tot, off);
        pos += __shfl_down(pos, off);
    }
    if (lane == 0) {
        int wid = (blockIdx.y * GRID_I + blockIdx.x) * 4 + w;
        partials[wid * 2]     = tot;
        partials[wid * 2 + 1] = pos;
    }
}

// ---------------------------------------------------------------------------
// Kernel 3: reduce partial pairs, loss = -log(pos/tot)/hw^2
// ---------------------------------------------------------------------------
__global__ __launch_bounds__(256) void finalize_kernel(const float* __restrict__ partials,
                                                       float* __restrict__ out) {
    double tot = 0.0, pos = 0.0;
    int t = threadIdx.x;
    for (int i = t; i < NPART; i += 256) {
        tot += (double)partials[i * 2];
        pos += (double)partials[i * 2 + 1];
    }
#pragma unroll
    for (int off = 32; off; off >>= 1) {
        tot += __shfl_down(tot, off);
        pos += __shfl_down(pos, off);
    }
    __shared__ double rt[4], rp[4];
    int w = t >> 6, lane = t & 63;
    if (lane == 0) { rt[w] = tot; rp[w] = pos; }
    __syncthreads();
    if (t == 0) {
        double T = rt[0] + rt[1] + rt[2] + rt[3];
        double P = rp[0] + rp[1] + rp[2] + rp[3];
        double hw2 = (double)HW * (double)HW;
        out[0] = (float)(-log(P / T) / hw2);
    }
}

extern "C" void kernel_launch(void* const* d_in, const int* in_sizes, int n_in,
                              void* d_out, int out_size, void* d_ws, size_t ws_size,
                              hipStream_t stream) {
    const float* x     = (const float*)d_in[0];   // (4,128,96,96) f32; only b=0,1 used
    const int*   label = (const int*)d_in[1];     // (4,1,96,96) i32; only b=0,1 used
    float*       out   = (float*)d_out;

    bf16*  feat  = (bf16*)d_ws;                       // feat1 (pre-scaled), feat2
    float* parts = (float*)((char*)d_ws + 2 * (size_t)HW * CDIM * sizeof(bf16));

    dim3 g1(HW / 64, CDIM / 64, 2);
    prep_kernel<<<g1, 256, 0, stream>>>(x, feat);

    dim3 g2(GRID_I, GRID_J);
    simsum_kernel<<<g2, 256, 0, stream>>>(feat, feat + (size_t)HW * CDIM, label, parts);

    finalize_kernel<<<1, 256, 0, stream>>>(parts, out);
}

// Round 4
// 51.167 us; speedup vs baseline: 1.4648x; 1.4648x over previous
//
#include <hip/hip_runtime.h>
#include <hip/hip_bf16.h>

#define HW 9216
#define CDIM 128
#define BM 128                      // rows per block (4 waves x 32 rows)
#define BN 64                       // cols per tile
#define JT 8                        // tiles per block -> 512 cols/block
#define GRID_I (HW / BM)            // 72
#define GRID_J (HW / (BN * JT))     // 18
#define NPART (GRID_I * GRID_J * 4) // per-wave partial pairs
#define LDP (CDIM + 8)              // padded LDS stride (272B): all patterns <=2-way

using bf16 = __hip_bfloat16;
typedef __attribute__((ext_vector_type(4))) float f32x4;
typedef __attribute__((ext_vector_type(8))) short s16x8;

// exp(d/0.04) = exp2(d * log2(e)/0.04); scale folded into feat1 at prep time
#define EXP_SCALE 36.067376022224085f

#if __has_builtin(__builtin_amdgcn_exp2f)
#define FEXP2(x) __builtin_amdgcn_exp2f(x)
#else
#define FEXP2(x) exp2f(x)
#endif

// ---------------------------------------------------------------------------
// Kernel 1: x[b] [C][HW] f32 -> feat[b] [HW][C] bf16 (feat1 pre-scaled).
// ---------------------------------------------------------------------------
__global__ __launch_bounds__(256) void prep_kernel(const float* __restrict__ x,
                                                   bf16* __restrict__ feat) {
    __shared__ float tile[64][65];
    const float* xs = x + (size_t)blockIdx.z * CDIM * HW;
    bf16* fs = feat + (size_t)blockIdx.z * HW * CDIM;
    float scale = (blockIdx.z == 0) ? EXP_SCALE : 1.0f;

    int p0 = blockIdx.x * 64;
    int c0 = blockIdx.y * 64;
    int t  = threadIdx.x;

    int pc = t & 63;
    int cr = t >> 6;
#pragma unroll
    for (int i = 0; i < 16; ++i) {
        int cl = cr + i * 4;
        tile[cl][pc] = xs[(size_t)(c0 + cl) * HW + p0 + pc];
    }
    __syncthreads();

    int cc = t & 63;
    int pr = t >> 6;
#pragma unroll
    for (int i = 0; i < 16; ++i) {
        int pl = pr + i * 4;
        fs[(size_t)(p0 + pl) * CDIM + c0 + cc] = __float2bfloat16(tile[cc][pl] * scale);
    }
}

// ---------------------------------------------------------------------------
// Kernel 2: 128-row band x 512 cols per block. A frags register-resident;
// B tiles (64 rows) double-buffered in LDS, T14 async stage (load regs early,
// ds_write after compute barrier), raw s_barrier (no vmcnt-drain syncthreads).
// grid = (72, 18), block = 256 (4 waves). Per-wave partials.
// ---------------------------------------------------------------------------
__global__ __launch_bounds__(256) void simsum_kernel(const bf16* __restrict__ feat1,
                                                     const bf16* __restrict__ feat2,
                                                     const int* __restrict__ label,
                                                     float* __restrict__ partials) {
    __shared__ bf16 Bs[2][BN][LDP];
    __shared__ int  labs[JT * BN];     // 512 column labels for this block
    __shared__ float red[8];

    int t    = threadIdx.x;
    int w    = t >> 6;
    int lane = t & 63;
    int lr   = lane & 15;        // fragment row/col lane index
    int kg   = lane >> 4;        // 0..3 k-subgroup

    int i0 = blockIdx.x * BM;
    int jb = blockIdx.y * (JT * BN);

    // A fragments (pre-scaled feat1), persistent: af[m][ks]; wave owns 32 rows
    s16x8 af[2][4];
#pragma unroll
    for (int m = 0; m < 2; ++m) {
        const bf16* arow = &feat1[(size_t)(i0 + w * 32 + m * 16 + lr) * CDIM + kg * 8];
#pragma unroll
        for (int ks = 0; ks < 4; ++ks)
            af[m][ks] = *(const s16x8*)(arow + ks * 32);
    }

    // row labels for accumulator rows: row = i0 + w*32 + m*16 + kg*4 + r2
    int g1v[2][4];
#pragma unroll
    for (int m = 0; m < 2; ++m)
#pragma unroll
        for (int r2 = 0; r2 < 4; ++r2)
            g1v[m][r2] = label[i0 + w * 32 + m * 16 + kg * 4 + r2];

    // column labels -> LDS (once)
    const int* lab2 = label + HW;
    {
        int la = lab2[jb + t];
        int lb = lab2[jb + 256 + t];
        labs[t]       = la;
        labs[t + 256] = lb;
    }

    // staging: 64 rows x 256B per tile; thread covers 4 rows' 16B chunks
    int srow = t >> 4;           // 0..15
    int sch8 = (t & 15) * 8;     // bf16 col offset
    s16x8 rb[4];

    auto load_tile = [&](int tt) {
#pragma unroll
        for (int q = 0; q < 4; ++q)
            rb[q] = *(const s16x8*)(&feat2[(size_t)(jb + tt * BN + srow + q * 16) * CDIM + sch8]);
    };
    auto write_tile = [&](int bsel) {
#pragma unroll
        for (int q = 0; q < 4; ++q)
            *(s16x8*)(&Bs[bsel][srow + q * 16][sch8]) = rb[q];
    };

    // prologue: fill both buffers, prefetch tile 2 into regs
    load_tile(0);  write_tile(0);
    load_tile(1);  write_tile(1);
    load_tile(2);
    asm volatile("s_waitcnt lgkmcnt(0)" ::: "memory");
    __builtin_amdgcn_sched_barrier(0);
    __builtin_amdgcn_s_barrier();        // buffers 0,1 + labs visible to all

    float tot0 = 0.f, tot1 = 0.f, pos0 = 0.f, pos1 = 0.f;

#pragma unroll
    for (int tt = 0; tt < JT; ++tt) {
        // column labels for this tile (broadcast ds_read)
        int g2v[4];
#pragma unroll
        for (int n = 0; n < 4; ++n)
            g2v[n] = labs[tt * BN + n * 16 + lr];

        // MFMA: 2m x 4n x 4ks from Bs[tt&1]
        f32x4 acc[2][4] = {};
#pragma unroll
        for (int ks = 0; ks < 4; ++ks) {
            int kbase = ks * 32 + kg * 8;
            s16x8 bfv[4];
#pragma unroll
            for (int n = 0; n < 4; ++n)
                bfv[n] = *(const s16x8*)(&Bs[tt & 1][n * 16 + lr][kbase]);
#pragma unroll
            for (int m = 0; m < 2; ++m)
#pragma unroll
                for (int n = 0; n < 4; ++n)
                    acc[m][n] = __builtin_amdgcn_mfma_f32_16x16x32_bf16(af[m][ks], bfv[n], acc[m][n], 0, 0, 0);
        }

        __builtin_amdgcn_sched_barrier(0);
        __builtin_amdgcn_s_barrier();    // (B) all waves done reading Bs[tt&1]

        // T14: write prefetched tile tt+2 into the freed buffer; issue tt+3 loads
        if (tt + 2 < JT) write_tile(tt & 1);
        if (tt + 3 < JT) load_tile(tt + 3);

        // epilogue: exp + masked/total accumulate (overlaps staging latency)
#pragma unroll
        for (int n = 0; n < 4; ++n) {
#pragma unroll
            for (int r2 = 0; r2 < 4; ++r2) {
                float e0 = FEXP2(acc[0][n][r2]);
                tot0 += e0;
                pos0 += (g1v[0][r2] == g2v[n]) ? e0 : 0.f;
                float e1 = FEXP2(acc[1][n][r2]);
                tot1 += e1;
                pos1 += (g1v[1][r2] == g2v[n]) ? e1 : 0.f;
            }
        }

        if (tt + 1 < JT) {
            asm volatile("s_waitcnt lgkmcnt(0)" ::: "memory");   // my ds_writes done
            __builtin_amdgcn_sched_barrier(0);
            __builtin_amdgcn_s_barrier(); // (A) next buffer fully written by all
        }
    }

    float tot = tot0 + tot1, pos = pos0 + pos1;
#pragma unroll
    for (int off = 32; off; off >>= 1) {
        tot += __shfl_down(tot, off);
        pos += __shfl_down(pos, off);
    }
    if (lane == 0) { red[w * 2] = tot; red[w * 2 + 1] = pos; }
    __syncthreads();
    if (t == 0) {
        float T4 = red[0] + red[2] + red[4] + red[6];
        float P4 = red[1] + red[3] + red[5] + red[7];
        int bid = blockIdx.y * GRID_I + blockIdx.x;
        partials[(bid * 4 + 0) * 2] = T4;   // keep layout simple: one pair per block
        partials[(bid * 4 + 0) * 2 + 1] = P4;
        partials[(bid * 4 + 1) * 2] = 0.f; partials[(bid * 4 + 1) * 2 + 1] = 0.f;
        partials[(bid * 4 + 2) * 2] = 0.f; partials[(bid * 4 + 2) * 2 + 1] = 0.f;
        partials[(bid * 4 + 3) * 2] = 0.f; partials[(bid * 4 + 3) * 2 + 1] = 0.f;
    }
}

// ---------------------------------------------------------------------------
// Kernel 3: reduce partial pairs, loss = -log(pos/tot)/hw^2
// ---------------------------------------------------------------------------
__global__ __launch_bounds__(256) void finalize_kernel(const float* __restrict__ partials,
                                                       float* __restrict__ out) {
    double tot = 0.0, pos = 0.0;
    int t = threadIdx.x;
    for (int i = t; i < NPART; i += 256) {
        tot += (double)partials[i * 2];
        pos += (double)partials[i * 2 + 1];
    }
#pragma unroll
    for (int off = 32; off; off >>= 1) {
        tot += __shfl_down(tot, off);
        pos += __shfl_down(pos, off);
    }
    __shared__ double rt[4], rp[4];
    int w = t >> 6, lane = t & 63;
    if (lane == 0) { rt[w] = tot; rp[w] = pos; }
    __syncthreads();
    if (t == 0) {
        double T = rt[0] + rt[1] + rt[2] + rt[3];
        double P = rp[0] + rp[1] + rp[2] + rp[3];
        double hw2 = (double)HW * (double)HW;
        out[0] = (float)(-log(P / T) / hw2);
    }
}

extern "C" void kernel_launch(void* const* d_in, const int* in_sizes, int n_in,
                              void* d_out, int out_size, void* d_ws, size_t ws_size,
                              hipStream_t stream) {
    const float* x     = (const float*)d_in[0];   // (4,128,96,96) f32; only b=0,1 used
    const int*   label = (const int*)d_in[1];     // (4,1,96,96) i32; only b=0,1 used
    float*       out   = (float*)d_out;

    bf16*  feat  = (bf16*)d_ws;                       // feat1 (pre-scaled), feat2
    float* parts = (float*)((char*)d_ws + 2 * (size_t)HW * CDIM * sizeof(bf16));

    dim3 g1(HW / 64, CDIM / 64, 2);
    prep_kernel<<<g1, 256, 0, stream>>>(x, feat);

    dim3 g2(GRID_I, GRID_J);
    simsum_kernel<<<g2, 256, 0, stream>>>(feat, feat + (size_t)HW * CDIM, label, parts);

    finalize_kernel<<<1, 256, 0, stream>>>(parts, out);
}

// Round 5
// 50.552 us; speedup vs baseline: 1.4826x; 1.0122x over previous
//
#include <hip/hip_runtime.h>
#include <hip/hip_bf16.h>

#define HW 9216
#define CDIM 128
#define BM 256                      // rows per block (8 waves x 32 rows)
#define BN 64                       // cols per tile
#define JT 4                        // tiles per block -> 256 cols/block
#define GRID_I (HW / BM)            // 36
#define GRID_J (HW / (BN * JT))     // 36
#define NPART (GRID_I * GRID_J)     // 1296 partial pairs (one per block)
#define LDP (CDIM + 8)              // padded LDS stride (272B)

using bf16 = __hip_bfloat16;
typedef __attribute__((ext_vector_type(16))) float f32x16;
typedef __attribute__((ext_vector_type(8))) short s16x8;

// exp(d/0.04) = exp2(d * log2(e)/0.04); scale folded into feat1 at prep time
#define EXP_SCALE 36.067376022224085f

#if __has_builtin(__builtin_amdgcn_exp2f)
#define FEXP2(x) __builtin_amdgcn_exp2f(x)
#else
#define FEXP2(x) exp2f(x)
#endif

// ---------------------------------------------------------------------------
// Kernel 1: x[b] [C][HW] f32 -> feat[b] [HW][C] bf16 (feat1 pre-scaled).
// ---------------------------------------------------------------------------
__global__ __launch_bounds__(256) void prep_kernel(const float* __restrict__ x,
                                                   bf16* __restrict__ feat) {
    __shared__ float tile[64][65];
    const float* xs = x + (size_t)blockIdx.z * CDIM * HW;
    bf16* fs = feat + (size_t)blockIdx.z * HW * CDIM;
    float scale = (blockIdx.z == 0) ? EXP_SCALE : 1.0f;

    int p0 = blockIdx.x * 64;
    int c0 = blockIdx.y * 64;
    int t  = threadIdx.x;

    int pc = t & 63;
    int cr = t >> 6;
#pragma unroll
    for (int i = 0; i < 16; ++i) {
        int cl = cr + i * 4;
        tile[cl][pc] = xs[(size_t)(c0 + cl) * HW + p0 + pc];
    }
    __syncthreads();

    int cc = t & 63;
    int pr = t >> 6;
#pragma unroll
    for (int i = 0; i < 16; ++i) {
        int pl = pr + i * 4;
        fs[(size_t)(p0 + pl) * CDIM + c0 + cc] = __float2bfloat16(tile[cc][pl] * scale);
    }
}

// ---------------------------------------------------------------------------
// Kernel 2: 256-row band x 256 cols per block, 8 waves x 32 rows each.
// mfma_f32_32x32x16_bf16; A frags + row labels register-resident; B tiles
// (64 cols) double-buffered in LDS with T14 async stage + raw barriers.
// grid = (36, 36), block = 512. One partial pair per block.
// ---------------------------------------------------------------------------
__global__ __launch_bounds__(512, 4) void simsum_kernel(const bf16* __restrict__ feat1,
                                                        const bf16* __restrict__ feat2,
                                                        const int* __restrict__ label,
                                                        float* __restrict__ partials) {
    __shared__ bf16 Bs[2][BN][LDP];
    __shared__ float red[16];

    int t    = threadIdx.x;
    int w    = t >> 6;           // wave 0..7
    int lane = t & 63;
    int cl   = lane & 31;        // row/col lane index within fragment
    int hi   = lane >> 5;        // k-half select

    int i0  = blockIdx.x * BM;
    int jb  = blockIdx.y * (BN * JT);
    int r0w = i0 + w * 32;       // this wave's 32 output rows

    // A fragments (pre-scaled feat1): af[s] for k-step s; lane row = cl,
    // k = s*16 + hi*8 .. +8
    s16x8 af[8];
    {
        const bf16* arow = &feat1[(size_t)(r0w + cl) * CDIM + hi * 8];
#pragma unroll
        for (int s = 0; s < 8; ++s)
            af[s] = *(const s16x8*)(arow + s * 16);
    }

    // row labels for C rows: row = (reg&3) + 8*(reg>>2) + 4*hi  (reg 0..15)
    int4 g1i[4];
#pragma unroll
    for (int q = 0; q < 4; ++q)
        g1i[q] = *(const int4*)(&label[r0w + 4 * hi + 8 * q]);

    // staging: tile = 64 rows x 256B; 512 threads: thread covers rows srow, srow+32
    int srow = t >> 4;           // 0..31
    int sch8 = (t & 15) * 8;     // bf16 col offset
    s16x8 rb[2];

    auto load_tile = [&](int tt) {
        const bf16* base = &feat2[(size_t)(jb + tt * BN + srow) * CDIM + sch8];
        rb[0] = *(const s16x8*)(base);
        rb[1] = *(const s16x8*)(base + 32 * CDIM);
    };
    auto write_tile = [&](int b) {
        *(s16x8*)(&Bs[b][srow][sch8])      = rb[0];
        *(s16x8*)(&Bs[b][srow + 32][sch8]) = rb[1];
    };

    // prologue: fill both buffers, prefetch tile 2 into regs
    load_tile(0);  write_tile(0);
    load_tile(1);  write_tile(1);
    load_tile(2);
    asm volatile("s_waitcnt lgkmcnt(0)" ::: "memory");
    __builtin_amdgcn_sched_barrier(0);
    __builtin_amdgcn_s_barrier();

    const int* lab2 = label + HW;
    float tot0 = 0.f, tot1 = 0.f, pos0 = 0.f, pos1 = 0.f;

#pragma unroll
    for (int tt = 0; tt < JT; ++tt) {
        // column labels for this tile's two 32-col blocks (coalesced, cached)
        int g2a = lab2[jb + tt * BN + cl];
        int g2b = lab2[jb + tt * BN + 32 + cl];

        // MFMA: 2 independent 32x32 acc chains over 8 k-steps
        f32x16 acc0 = {}, acc1 = {};
#pragma unroll
        for (int s = 0; s < 8; ++s) {
            const bf16* bp = &Bs[tt & 1][cl][s * 16 + hi * 8];
            s16x8 b0 = *(const s16x8*)(bp);
            s16x8 b1 = *(const s16x8*)(bp + (size_t)32 * LDP);
            acc0 = __builtin_amdgcn_mfma_f32_32x32x16_bf16(af[s], b0, acc0, 0, 0, 0);
            acc1 = __builtin_amdgcn_mfma_f32_32x32x16_bf16(af[s], b1, acc1, 0, 0, 0);
        }

        __builtin_amdgcn_sched_barrier(0);
        __builtin_amdgcn_s_barrier();    // all waves done reading Bs[tt&1]

        // T14: commit prefetched tile tt+2 into freed buffer; issue tt+3 loads
        if (tt + 2 < JT) write_tile(tt & 1);
        if (tt + 3 < JT) load_tile(tt + 3);

        // epilogue: exp + masked/total accumulate (overlaps staging latency)
#pragma unroll
        for (int r = 0; r < 16; ++r) {
            int g1 = ((const int*)g1i)[r];
            float e0 = FEXP2(acc0[r]);
            tot0 += e0;
            pos0 += (g1 == g2a) ? e0 : 0.f;
            float e1 = FEXP2(acc1[r]);
            tot1 += e1;
            pos1 += (g1 == g2b) ? e1 : 0.f;
        }

        if (tt + 1 < JT) {
            asm volatile("s_waitcnt lgkmcnt(0)" ::: "memory");   // ds_writes done
            __builtin_amdgcn_sched_barrier(0);
            __builtin_amdgcn_s_barrier(); // next buffer fully written by all
        }
    }

    float tot = tot0 + tot1, pos = pos0 + pos1;
#pragma unroll
    for (int off = 32; off; off >>= 1) {
        tot += __shfl_down(tot, off);
        pos += __shfl_down(pos, off);
    }
    if (lane == 0) { red[w * 2] = tot; red[w * 2 + 1] = pos; }
    __syncthreads();
    if (t == 0) {
        float T = 0.f, P = 0.f;
#pragma unroll
        for (int q = 0; q < 8; ++q) { T += red[q * 2]; P += red[q * 2 + 1]; }
        int bid = blockIdx.y * GRID_I + blockIdx.x;
        partials[bid * 2]     = T;
        partials[bid * 2 + 1] = P;
    }
}

// ---------------------------------------------------------------------------
// Kernel 3: reduce partial pairs, loss = -log(pos/tot)/hw^2
// ---------------------------------------------------------------------------
__global__ __launch_bounds__(256) void finalize_kernel(const float* __restrict__ partials,
                                                       float* __restrict__ out) {
    double tot = 0.0, pos = 0.0;
    int t = threadIdx.x;
    for (int i = t; i < NPART; i += 256) {
        tot += (double)partials[i * 2];
        pos += (double)partials[i * 2 + 1];
    }
#pragma unroll
    for (int off = 32; off; off >>= 1) {
        tot += __shfl_down(tot, off);
        pos += __shfl_down(pos, off);
    }
    __shared__ double rt[4], rp[4];
    int w = t >> 6, lane = t & 63;
    if (lane == 0) { rt[w] = tot; rp[w] = pos; }
    __syncthreads();
    if (t == 0) {
        double T = rt[0] + rt[1] + rt[2] + rt[3];
        double P = rp[0] + rp[1] + rp[2] + rp[3];
        double hw2 = (double)HW * (double)HW;
        out[0] = (float)(-log(P / T) / hw2);
    }
}

extern "C" void kernel_launch(void* const* d_in, const int* in_sizes, int n_in,
                              void* d_out, int out_size, void* d_ws, size_t ws_size,
                              hipStream_t stream) {
    const float* x     = (const float*)d_in[0];   // (4,128,96,96) f32; only b=0,1 used
    const int*   label = (const int*)d_in[1];     // (4,1,96,96) i32; only b=0,1 used
    float*       out   = (float*)d_out;

    bf16*  feat  = (bf16*)d_ws;                       // feat1 (pre-scaled), feat2
    float* parts = (float*)((char*)d_ws + 2 * (size_t)HW * CDIM * sizeof(bf16));

    dim3 g1(HW / 64, CDIM / 64, 2);
    prep_kernel<<<g1, 256, 0, stream>>>(x, feat);

    dim3 g2(GRID_I, GRID_J);
    simsum_kernel<<<g2, 512, 0, stream>>>(feat, feat + (size_t)HW * CDIM, label, parts);

    finalize_kernel<<<1, 256, 0, stream>>>(parts, out);
}